// Round 10
// baseline (328.212 us; speedup 1.0000x reference)
//
#include <hip/hip_runtime.h>

typedef __bf16 bf16_8 __attribute__((ext_vector_type(8)));
typedef float  f32x4  __attribute__((ext_vector_type(4)));
typedef float  f32x3  __attribute__((ext_vector_type(3), aligned(4)));

#define INV_SQRT3f 0.57735026918962576f

// R14: R13's regression was store-path traffic amplification (FETCH 64->103,
// WRITE 125->212 MB: scattered 4B/12B NT stores interleaved with staggered
// loads -> partial-line evictions -> RMW + re-writebacks), NOT the stagger
// (regs stayed 84, no spill). Confirmed model: dur == hbm_bytes / ~2.1 TB/s
// in every round. R11's staged 1KB-coalesced drain is the only leak-free
// store path (WRITE = 125.0 exact).
//
// R14 = R13's pair-per-wave zero-reg stagger + R11's staged store path:
//  * private 5KB/wave staging (4-row x 4-pass), coexists with weights ->
//    no 2nd barrier, waves desync; drain = 64 lanes x 16B = 1KB contiguous NT.
//  * w01 -> linear global fragment path (1 load -> 3 MFMAs; R9/R12-proven)
//    to fund staging LDS: 32KB w00 + 4x5KB = 52KB -> 3 blocks/CU.
//  * grid 782 blocks ~= 3.05/CU: whole problem in ONE residency generation.
//  * bias hoisted to 8 regs.
//
// ws layout (bf16): w00 swz [c=128][q^(c&15)][8] @0 ; w01 linear [c=64][q=16][8] @16384
//                   w11 linear [c=128][q=8][8] @24576 ; w10 linear [64][8][8] @32768
// chunk (c,q) element j = W[(q*8+j)*ncols + c]  (B[k][n] layout, k=q*8+j, n=c)
//
// MFMA 16x16x32 bf16 layouts (HW-verified per guide):
//   A: A[m = lane&15][k = (lane>>4)*8 + j], j=0..7
//   B: B[k = (lane>>4)*8 + j][n = lane&15]
//   C/D: D[row = (lane>>4)*4 + r][col = lane&15], r = reg 0..3

__global__ void tp_convert_weights(
    const float* __restrict__ W00, const float* __restrict__ W01,
    const float* __restrict__ W10, const float* __restrict__ W11,
    __bf16* __restrict__ ws)
{
    const int chunk = blockIdx.x * blockDim.x + threadIdx.x;
    bf16_8 v;
    if (chunk < 2048) {                       // W00: 128 cols x K=128, swizzled
        const int c = chunk >> 4, q = chunk & 15;
#pragma unroll
        for (int j = 0; j < 8; ++j) v[j] = (__bf16)W00[(q * 8 + j) * 128 + c];
        *(bf16_8*)(ws + (c * 16 + (q ^ (c & 15))) * 8) = v;
    } else if (chunk < 3072) {                // W01: 64 cols x K=128, LINEAR
        const int idx = chunk - 2048;
        const int c = idx >> 4, q = idx & 15;
#pragma unroll
        for (int j = 0; j < 8; ++j) v[j] = (__bf16)W01[(q * 8 + j) * 64 + c];
        *(bf16_8*)(ws + 16384 + idx * 8) = v;   // idx = c*16+q
    } else if (chunk < 4096) {                // W11: 128 cols x K=64, linear
        const int idx = chunk - 3072;
        const int c = idx >> 3, q = idx & 7;
#pragma unroll
        for (int j = 0; j < 8; ++j) v[j] = (__bf16)W11[(q * 8 + j) * 128 + c];
        *(bf16_8*)(ws + 24576 + idx * 8) = v;   // idx = c*8+q
    } else if (chunk < 4608) {                // W10: 64 cols x K=64, linear
        const int idx = chunk - 4096;
        const int c = idx >> 3, q = idx & 7;
#pragma unroll
        for (int j = 0; j < 8; ++j) v[j] = (__bf16)W10[(q * 8 + j) * 64 + c];
        *(bf16_8*)(ws + 32768 + idx * 8) = v;
    }
}

// ---- macros: all array indices compile-time constant (no scratch) ----
#define LOAD_S1(P1, D2, S) do {                                               \
    int _row = (S) * 16 + mh;  if (_row >= N) _row = N - 1;                   \
    const float* _r1 = din1 + _row * 320 + 8 * kq;                            \
    _Pragma("unroll")                                                         \
    for (int _t = 0; _t < 4; ++_t) {                                          \
        P1[2 * _t]     = *(const f32x4*)(_r1 + 32 * _t);                      \
        P1[2 * _t + 1] = *(const f32x4*)(_r1 + 32 * _t + 4);                  \
    }                                                                         \
    D2 = *(const f32x4*)(din2 + _row * 4);                                    \
} while (0)

#define LOAD_S2(P2, S) do {                                                   \
    int _row = (S) * 16 + mh;  if (_row >= N) _row = N - 1;                   \
    const float* _r2 = din1 + _row * 320 + 128 + 24 * kq;                     \
    _Pragma("unroll")                                                         \
    for (int _h = 0; _h < 2; ++_h)                                            \
        _Pragma("unroll")                                                     \
        for (int _q = 0; _q < 6; ++_q)                                        \
            P2[6 * _h + _q] = *(const f32x4*)(_r2 + 96 * _h + 4 * _q);        \
} while (0)

#define PH1(P1, D2) do {                                                      \
    _Pragma("unroll")                                                         \
    for (int _i = 0; _i < 8; ++_i) accA[_i] = (f32x4)0.0f;                    \
    _Pragma("unroll")                                                         \
    for (int _k = 0; _k < 3; ++_k)                                            \
        _Pragma("unroll")                                                     \
        for (int _i = 0; _i < 4; ++_i) accV[_k][_i] = (f32x4)0.0f;            \
    _Pragma("unroll")                                                         \
    for (int _s = 0; _s < 4; ++_s) {                                          \
        const f32x4 _x0 = P1[2 * _s];                                         \
        const f32x4 _x1 = P1[2 * _s + 1];                                     \
        float _xx[8] = {_x0.x, _x0.y, _x0.z, _x0.w, _x1.x, _x1.y, _x1.z, _x1.w}; \
        bf16_8 _as2, _av0, _av1, _av2;                                        \
        _Pragma("unroll")                                                     \
        for (int _j = 0; _j < 8; ++_j) {                                      \
            _as2[_j] = (__bf16)(D2.x * _xx[_j]);                              \
            _av0[_j] = (__bf16)(D2.y * _xx[_j]);                              \
            _av1[_j] = (__bf16)(D2.z * _xx[_j]);                              \
            _av2[_j] = (__bf16)(D2.w * _xx[_j]);                              \
        }                                                                     \
        const int _q = 4 * _s + kq;                                           \
        _Pragma("unroll")                                                     \
        for (int _nt = 0; _nt < 8; ++_nt) {                                   \
            const int _c = _nt * 16 + mh;                                     \
            bf16_8 _b = *(const bf16_8*)(sw00 + (_c * 16 + (_q ^ mh)) * 8);   \
            accA[_nt] = __builtin_amdgcn_mfma_f32_16x16x32_bf16(_as2, _b, accA[_nt], 0, 0, 0); \
        }                                                                     \
        _Pragma("unroll")                                                     \
        for (int _nt = 0; _nt < 4; ++_nt) {                                   \
            const int _c = _nt * 16 + mh;                                     \
            bf16_8 _b = *(const bf16_8*)(w01g + (_c * 16 + _q) * 8);          \
            accV[0][_nt] = __builtin_amdgcn_mfma_f32_16x16x32_bf16(_av0, _b, accV[0][_nt], 0, 0, 0); \
            accV[1][_nt] = __builtin_amdgcn_mfma_f32_16x16x32_bf16(_av1, _b, accV[1][_nt], 0, 0, 0); \
            accV[2][_nt] = __builtin_amdgcn_mfma_f32_16x16x32_bf16(_av2, _b, accV[2][_nt], 0, 0, 0); \
        }                                                                     \
    }                                                                         \
} while (0)

#define PH2(P2, D2) do {                                                      \
    _Pragma("unroll")                                                         \
    for (int _s = 0; _s < 2; ++_s) {                                          \
        float _b24[24];                                                       \
        _Pragma("unroll")                                                     \
        for (int _qq = 0; _qq < 6; ++_qq) {                                   \
            const f32x4 _t4 = P2[6 * _s + _qq];                               \
            _b24[4 * _qq]     = _t4.x; _b24[4 * _qq + 1] = _t4.y;             \
            _b24[4 * _qq + 2] = _t4.z; _b24[4 * _qq + 3] = _t4.w;             \
        }                                                                     \
        bf16_8 _at, _ac0, _ac1, _ac2;                                         \
        _Pragma("unroll")                                                     \
        for (int _j = 0; _j < 8; ++_j) {                                      \
            const float _e0 = _b24[3 * _j], _e1 = _b24[3 * _j + 1], _e2 = _b24[3 * _j + 2]; \
            _at[_j]  = (__bf16)(INV_SQRT3f * (_e0 * D2.y + _e1 * D2.z + _e2 * D2.w)); \
            _ac0[_j] = (__bf16)(D2.x * _e0);                                  \
            _ac1[_j] = (__bf16)(D2.x * _e1);                                  \
            _ac2[_j] = (__bf16)(D2.x * _e2);                                  \
        }                                                                     \
        const int _q = 4 * _s + kq;                                           \
        _Pragma("unroll")                                                     \
        for (int _nt = 0; _nt < 8; ++_nt) {                                   \
            const int _c = _nt * 16 + mh;                                     \
            bf16_8 _b = *(const bf16_8*)(w11g + (_c * 8 + _q) * 8);           \
            accA[_nt] = __builtin_amdgcn_mfma_f32_16x16x32_bf16(_at, _b, accA[_nt], 0, 0, 0); \
        }                                                                     \
        _Pragma("unroll")                                                     \
        for (int _nt = 0; _nt < 4; ++_nt) {                                   \
            const int _c = _nt * 16 + mh;                                     \
            bf16_8 _b = *(const bf16_8*)(w10g + (_c * 8 + _q) * 8);           \
            accV[0][_nt] = __builtin_amdgcn_mfma_f32_16x16x32_bf16(_ac0, _b, accV[0][_nt], 0, 0, 0); \
            accV[1][_nt] = __builtin_amdgcn_mfma_f32_16x16x32_bf16(_ac1, _b, accV[1][_nt], 0, 0, 0); \
            accV[2][_nt] = __builtin_amdgcn_mfma_f32_16x16x32_bf16(_ac2, _b, accV[2][_nt], 0, 0, 0); \
        }                                                                     \
    }                                                                         \
} while (0)

// staged coalesced epilogue: 4 passes x 4 rows; private 5KB stgw; drain = 1KB/instr
#define EPI(S) do {                                                           \
    const int _r0 = (S) * 16;                                                 \
    if (_r0 + 16 <= N) {                                                      \
        _Pragma("unroll")                                                     \
        for (int _p = 0; _p < 4; ++_p) {                                      \
            asm volatile("s_waitcnt lgkmcnt(0)" ::: "memory");                \
            if (kq == _p) {                                                   \
                _Pragma("unroll")                                             \
                for (int _nt = 0; _nt < 8; ++_nt) {                           \
                    _Pragma("unroll")                                         \
                    for (int _r = 0; _r < 4; ++_r) {                          \
                        const int _ch = (_nt * 4 + (mh >> 2)) ^ _r;           \
                        stgw[_r * 320 + _ch * 4 + (mh & 3)] = accA[_nt][_r] + biasr[_nt]; \
                    }                                                         \
                }                                                             \
                _Pragma("unroll")                                             \
                for (int _nt = 0; _nt < 4; ++_nt) {                           \
                    _Pragma("unroll")                                         \
                    for (int _r = 0; _r < 4; ++_r) {                          \
                        _Pragma("unroll")                                     \
                        for (int _k = 0; _k < 3; ++_k) {                      \
                            const int _f = 128 + 3 * (_nt * 16 + mh) + _k;    \
                            const int _ch = (_f >> 2) ^ _r;                   \
                            stgw[_r * 320 + _ch * 4 + (_f & 3)] = accV[_k][_nt][_r]; \
                        }                                                     \
                    }                                                         \
                }                                                             \
            }                                                                 \
            asm volatile("s_waitcnt lgkmcnt(0)" ::: "memory");                \
            __builtin_amdgcn_sched_barrier(0);                                \
            float* _gbase = out + (_r0 + _p * 4) * 320;                       \
            _Pragma("unroll")                                                 \
            for (int _i = 0; _i < 5; ++_i) {                                  \
                const int _v  = _i * 64 + lane;                               \
                const int _rw = _v / 80;                                      \
                const int _ch = (_v % 80) ^ _rw;                              \
                f32x4 _d = *(const f32x4*)(stgw + _rw * 320 + _ch * 4);       \
                __builtin_nontemporal_store(_d, (f32x4*)(_gbase + _v * 4));   \
            }                                                                 \
        }                                                                     \
    } else {                                                                  \
        const int _rowg0 = _r0 + 4 * kq;                                      \
        _Pragma("unroll")                                                     \
        for (int _nt = 0; _nt < 8; ++_nt) {                                   \
            _Pragma("unroll")                                                 \
            for (int _r = 0; _r < 4; ++_r) {                                  \
                const int _rowg = _rowg0 + _r;                                \
                if (_rowg < N)                                                \
                    __builtin_nontemporal_store(accA[_nt][_r] + biasr[_nt],   \
                                                out + _rowg * 320 + _nt * 16 + mh); \
            }                                                                 \
        }                                                                     \
        _Pragma("unroll")                                                     \
        for (int _r = 0; _r < 4; ++_r) {                                      \
            const int _rowg = _rowg0 + _r;                                    \
            if (_rowg < N) {                                                  \
                _Pragma("unroll")                                             \
                for (int _nt = 0; _nt < 4; ++_nt) {                           \
                    const int _w = _nt * 16 + mh;                             \
                    f32x3 _o;                                                 \
                    _o.x = accV[0][_nt][_r];                                  \
                    _o.y = accV[1][_nt][_r];                                  \
                    _o.z = accV[2][_nt][_r];                                  \
                    __builtin_nontemporal_store(_o,                           \
                        (f32x3*)(out + _rowg * 320 + 128 + 3 * _w));          \
                }                                                             \
            }                                                                 \
        }                                                                     \
    }                                                                         \
} while (0)

__global__ __launch_bounds__(256, 3) void tp_main_kernel(
    const float* __restrict__ din1, const float* __restrict__ din2,
    const __bf16* __restrict__ wsw, const float* __restrict__ bias,
    float* __restrict__ out, int N, int npairs)
{
    // 52 KB: 32 KB swizzled w00 + 4 x 5 KB per-wave output staging
    __shared__ __attribute__((aligned(16))) __bf16 smem[26624];
    const __bf16* sw00 = smem;                               // 16384 elems
    float* stgbase = (float*)(smem + 16384);                 // 5120 f32

    const int tid  = threadIdx.x;
    const int wid  = (blockIdx.x << 2) + (tid >> 6);         // pair id
    const int lane = tid & 63;
    const int mh   = lane & 15;
    const int kq   = lane >> 4;
    float* stgw = stgbase + (tid >> 6) * 1280;               // private 5 KB

    const __bf16* __restrict__ w01g = wsw + 16384;
    const __bf16* __restrict__ w11g = wsw + 24576;
    const __bf16* __restrict__ w10g = wsw + 32768;

    // clamped pair for tail waves (prefetch harmlessly, skip compute)
    const int spair = wid < npairs ? wid : npairs - 1;
    const int sA = 2 * spair, sB = 2 * spair + 1;

    // ---- 1) LDS-fill loads (w00 only, 32 KB; barrier-critical) ----
    f32x4 fill[8];
    {
        const f32x4* s = (const f32x4*)wsw;
#pragma unroll
        for (int i = 0; i < 8; ++i) fill[i] = s[tid + 256 * i];
    }

    // ---- 2) strip-A register prefetch burst (hides under fill+barrier) ----
    f32x4 p1[8], p2[12], d2A, d2B;
    LOAD_S1(p1, d2A, sA);
    LOAD_S2(p2, sA);

    // ---- 3) LDS writes (wait only on fill loads) + single barrier ----
    {
        f32x4* d = (f32x4*)smem;
#pragma unroll
        for (int i = 0; i < 8; ++i) d[tid + 256 * i] = fill[i];
    }
    __syncthreads();

    if (wid < npairs) {
        float biasr[8];
#pragma unroll
        for (int i = 0; i < 8; ++i) biasr[i] = bias[i * 16 + mh];

        f32x4 accA[8];      // out0: 128 cols
        f32x4 accV[3][4];   // outv: 64 w-cols x 3 vector comps

        // ---- strip A, with zero-cost staggered reload of p1/p2 for B ----
        PH1(p1, d2A);            // consumes p1
        LOAD_S1(p1, d2B, sB);    // reload same regs; flies under PH2+EPI
        PH2(p2, d2A);            // consumes p2
        LOAD_S2(p2, sB);         // reload same regs; flies under EPI
        EPI(sA);

        // ---- strip B ----
        PH1(p1, d2B);
        PH2(p2, d2B);
        EPI(sB);
    }
}

extern "C" void kernel_launch(void* const* d_in, const int* in_sizes, int n_in,
                              void* d_out, int out_size, void* d_ws, size_t ws_size,
                              hipStream_t stream)
{
    const float* din1 = (const float*)d_in[0];
    const float* din2 = (const float*)d_in[1];
    const float* W00  = (const float*)d_in[2];
    const float* W01  = (const float*)d_in[3];
    const float* W10  = (const float*)d_in[4];
    const float* W11  = (const float*)d_in[5];
    const float* bias = (const float*)d_in[6];
    float* outp = (float*)d_out;
    __bf16* ws = (__bf16*)d_ws;

    const int N = in_sizes[0] / 320;
    const int npairs  = (N + 31) / 32;          // 32 rows (2 strips) per wave
    const int nblocks = (npairs + 3) / 4;       // 4 waves per 256-thread block

    // 4608 weight chunks, one bf16_8 per thread
    hipLaunchKernelGGL(tp_convert_weights, dim3(18), dim3(256), 0, stream,
                       W00, W01, W10, W11, ws);
    hipLaunchKernelGGL(tp_main_kernel, dim3(nblocks), dim3(256), 0, stream,
                       din1, din2, ws, bias, outp, N, npairs);
}

// Round 11
// 258.106 us; speedup vs baseline: 1.2716x; 1.2716x over previous
//
#include <hip/hip_runtime.h>

typedef __bf16 bf16_8 __attribute__((ext_vector_type(8)));
typedef float  f32x4  __attribute__((ext_vector_type(4)));
typedef float  f32x3  __attribute__((ext_vector_type(3), aligned(4)));

#define INV_SQRT3f 0.57735026918962576f

// R15: exact revert to R11 — the measured optimum of the 11-round search.
// Final model (held in all 11 rounds): dur == hbm_bytes / ~2.1 TB/s.
// R11 is the unique structure with zero write amplification (WRITE=125.0MB
// exact): loads fully complete -> compute -> staged 1KB-coalesced NT drains.
// Every overlap attempt (R8 loop, R12-R14 staggered 2-strip) amplified
// traffic (interleaved reads force early flushes of partially-combined NT
// write sectors; ECC RMW raises FETCH in lockstep) and regressed.
// R11 sits at its own traffic floor: (64+125)MB / 2.05 TB/s = 92us predicted,
// 95.3us measured.
//
// Structure: 256-thr blocks, 48KB LDS (w00+w01 XOR-swizzled, filled by 16B
// vector memcpy from pre-converted d_ws), w11/w10 fragments from L2-hot
// global, full register prefetch of din1/din2 before the single barrier,
// one 16-row strip per wave, staged coalesced epilogue reusing dead weight
// LDS (two 8-row passes, 1KB-contiguous NT stores).
//
// ws layout (bf16): w00 swz [c=128][q^(c&15)][8] @0 ; w01 swz [64][16][8] @16384
//                   w11 linear [c=128][q=8][8] @24576 ; w10 linear [64][8][8] @32768
// chunk (c,q) element j = W[(q*8+j)*ncols + c]  (B[k][n] layout, k=q*8+j, n=c)
//
// MFMA 16x16x32 bf16 layouts (HW-verified per guide):
//   A: A[m = lane&15][k = (lane>>4)*8 + j], j=0..7
//   B: B[k = (lane>>4)*8 + j][n = lane&15]
//   C/D: D[row = (lane>>4)*4 + r][col = lane&15], r = reg 0..3

__global__ void tp_convert_weights(
    const float* __restrict__ W00, const float* __restrict__ W01,
    const float* __restrict__ W10, const float* __restrict__ W11,
    __bf16* __restrict__ ws)
{
    const int chunk = blockIdx.x * blockDim.x + threadIdx.x;
    bf16_8 v;
    if (chunk < 2048) {                       // W00: 128 cols x K=128, swizzled
        const int c = chunk >> 4, q = chunk & 15;
#pragma unroll
        for (int j = 0; j < 8; ++j) v[j] = (__bf16)W00[(q * 8 + j) * 128 + c];
        *(bf16_8*)(ws + (c * 16 + (q ^ (c & 15))) * 8) = v;
    } else if (chunk < 3072) {                // W01: 64 cols x K=128, swizzled
        const int idx = chunk - 2048;
        const int c = idx >> 4, q = idx & 15;
#pragma unroll
        for (int j = 0; j < 8; ++j) v[j] = (__bf16)W01[(q * 8 + j) * 64 + c];
        *(bf16_8*)(ws + 16384 + (c * 16 + (q ^ (c & 15))) * 8) = v;
    } else if (chunk < 4096) {                // W11: 128 cols x K=64, LINEAR (global path)
        const int idx = chunk - 3072;
        const int c = idx >> 3, q = idx & 7;
#pragma unroll
        for (int j = 0; j < 8; ++j) v[j] = (__bf16)W11[(q * 8 + j) * 128 + c];
        *(bf16_8*)(ws + 24576 + idx * 8) = v;   // idx = c*8+q
    } else if (chunk < 4608) {                // W10: 64 cols x K=64, linear
        const int idx = chunk - 4096;
        const int c = idx >> 3, q = idx & 7;
#pragma unroll
        for (int j = 0; j < 8; ++j) v[j] = (__bf16)W10[(q * 8 + j) * 64 + c];
        *(bf16_8*)(ws + 32768 + idx * 8) = v;
    }
}

__global__ __launch_bounds__(256, 3) void tp_main_kernel(
    const float* __restrict__ din1, const float* __restrict__ din2,
    const __bf16* __restrict__ wsw, const float* __restrict__ bias,
    float* __restrict__ out, int N, int nstrips)
{
    __shared__ __attribute__((aligned(16))) __bf16 smem[24576];  // 48 KB
    const __bf16* sw00 = smem;           // 16384 elems
    const __bf16* sw01 = smem + 16384;   //  8192 elems

    const int tid  = threadIdx.x;
    const int wid  = (blockIdx.x << 2) + (tid >> 6);
    const int lane = tid & 63;
    const int mh   = lane & 15;   // A row within strip / D col within tile
    const int kq   = lane >> 4;   // quad

    // clamped strip for tail waves (they prefetch harmlessly, skip compute)
    const int swid = wid < nstrips ? wid : nstrips - 1;
    int row = swid * 16 + mh;  if (row >= N) row = N - 1;
    const float* __restrict__ r1 = din1 + row * 320;

    // ---- 1) LDS-fill loads (barrier-critical, issue first): 48KB/block ----
    f32x4 fill[12];
    {
        const f32x4* s = (const f32x4*)wsw;
#pragma unroll
        for (int i = 0; i < 12; ++i) fill[i] = s[tid + 256 * i];
    }

    // ---- 2) din1/din2 register prefetch burst (hides under fill+barrier) ----
    f32x4 p1[8];    // phase-1 data: s=0..3, 8 floats each
#pragma unroll
    for (int s = 0; s < 4; ++s) {
        p1[2 * s]     = *(const f32x4*)(r1 + 32 * s + 8 * kq);
        p1[2 * s + 1] = *(const f32x4*)(r1 + 32 * s + 8 * kq + 4);
    }
    f32x4 p2[12];   // phase-2 data: s=0..1, 24 floats each
#pragma unroll
    for (int s = 0; s < 2; ++s)
#pragma unroll
        for (int qq = 0; qq < 6; ++qq)
            p2[6 * s + qq] = *(const f32x4*)(r1 + 128 + 96 * s + 24 * kq + 4 * qq);
    const f32x4 d2 = *(const f32x4*)(din2 + row * 4);
    const float s2 = d2.x;

    // ---- 3) LDS writes (wait only on fill loads) + barrier ----
    {
        f32x4* d = (f32x4*)smem;
#pragma unroll
        for (int i = 0; i < 12; ++i) d[tid + 256 * i] = fill[i];
    }
    __syncthreads();

    f32x4 accA[8];      // out0: 128 cols
    f32x4 accV[3][4];   // outv: 64 w-cols x 3 vector comps

    if (wid < nstrips) {
        const __bf16* __restrict__ w11g = wsw + 24576;
        const __bf16* __restrict__ w10g = wsw + 32768;

#pragma unroll
        for (int i = 0; i < 8; ++i) accA[i] = (f32x4)0.0f;
#pragma unroll
        for (int k = 0; k < 3; ++k)
#pragma unroll
            for (int i = 0; i < 4; ++i) accV[k][i] = (f32x4)0.0f;

        // ---- phase 1: s1 part (W00 -> accA K-steps 0..3; W01 -> accV) ----
#pragma unroll
        for (int s = 0; s < 4; ++s) {
            const f32x4 x0 = p1[2 * s];
            const f32x4 x1 = p1[2 * s + 1];
            float xx[8] = {x0.x, x0.y, x0.z, x0.w, x1.x, x1.y, x1.z, x1.w};
            bf16_8 as2, av0, av1, av2;
#pragma unroll
            for (int j = 0; j < 8; ++j) {
                as2[j] = (__bf16)(s2   * xx[j]);
                av0[j] = (__bf16)(d2.y * xx[j]);
                av1[j] = (__bf16)(d2.z * xx[j]);
                av2[j] = (__bf16)(d2.w * xx[j]);
            }
            const int q = 4 * s + kq;
#pragma unroll
            for (int nt = 0; nt < 8; ++nt) {
                const int c = nt * 16 + mh;
                bf16_8 b = *(const bf16_8*)(sw00 + (c * 16 + (q ^ mh)) * 8);
                accA[nt] = __builtin_amdgcn_mfma_f32_16x16x32_bf16(as2, b, accA[nt], 0, 0, 0);
            }
#pragma unroll
            for (int nt = 0; nt < 4; ++nt) {
                const int c = nt * 16 + mh;
                bf16_8 b = *(const bf16_8*)(sw01 + (c * 16 + (q ^ mh)) * 8);
                accV[0][nt] = __builtin_amdgcn_mfma_f32_16x16x32_bf16(av0, b, accV[0][nt], 0, 0, 0);
                accV[1][nt] = __builtin_amdgcn_mfma_f32_16x16x32_bf16(av1, b, accV[1][nt], 0, 0, 0);
                accV[2][nt] = __builtin_amdgcn_mfma_f32_16x16x32_bf16(av2, b, accV[2][nt], 0, 0, 0);
            }
        }

        // ---- phase 2: v part (W11 -> accA K-steps 4..5; W10 -> accV) ----
#pragma unroll
        for (int s = 0; s < 2; ++s) {
            float b24[24];
#pragma unroll
            for (int qq = 0; qq < 6; ++qq) {
                const f32x4 t4 = p2[6 * s + qq];
                b24[4 * qq]     = t4.x; b24[4 * qq + 1] = t4.y;
                b24[4 * qq + 2] = t4.z; b24[4 * qq + 3] = t4.w;
            }
            bf16_8 at, ac0, ac1, ac2;
#pragma unroll
            for (int j = 0; j < 8; ++j) {
                const float e0 = b24[3 * j], e1 = b24[3 * j + 1], e2 = b24[3 * j + 2];
                at[j]  = (__bf16)(INV_SQRT3f * (e0 * d2.y + e1 * d2.z + e2 * d2.w));
                ac0[j] = (__bf16)(s2 * e0);
                ac1[j] = (__bf16)(s2 * e1);
                ac2[j] = (__bf16)(s2 * e2);
            }
            const int q = 4 * s + kq;   // K=64 chunk index 0..7
#pragma unroll
            for (int nt = 0; nt < 8; ++nt) {
                const int c = nt * 16 + mh;
                bf16_8 b = *(const bf16_8*)(w11g + (c * 8 + q) * 8);
                accA[nt] = __builtin_amdgcn_mfma_f32_16x16x32_bf16(at, b, accA[nt], 0, 0, 0);
            }
#pragma unroll
            for (int nt = 0; nt < 4; ++nt) {
                const int c = nt * 16 + mh;
                bf16_8 b = *(const bf16_8*)(w10g + (c * 8 + q) * 8);
                accV[0][nt] = __builtin_amdgcn_mfma_f32_16x16x32_bf16(ac0, b, accV[0][nt], 0, 0, 0);
                accV[1][nt] = __builtin_amdgcn_mfma_f32_16x16x32_bf16(ac1, b, accV[1][nt], 0, 0, 0);
                accV[2][nt] = __builtin_amdgcn_mfma_f32_16x16x32_bf16(ac2, b, accV[2][nt], 0, 0, 0);
            }
        }
    }

    // ---- weights dead; reuse LDS for output staging ----
    __syncthreads();

    if (wid < nstrips) {
        float* stg = (float*)smem + (tid >> 6) * 2560;   // 10 KB per wave
        const int strip_row0 = wid * 16;

        if (strip_row0 + 16 <= N) {
            // full strip: staged coalesced path, two 8-row passes
#pragma unroll
            for (int p = 0; p < 2; ++p) {
                if (p == 1) {  // stg reused: pass-0 ds_reads must have landed
                    asm volatile("s_waitcnt lgkmcnt(0)" ::: "memory");
                }
                // --- stage: lanes with kq>>1 == p own local rows 4*(kq&1)+r ---
                if ((kq >> 1) == p) {
                    const int rl = 4 * (kq & 1);
#pragma unroll
                    for (int nt = 0; nt < 8; ++nt) {
                        const float bi = bias[nt * 16 + mh];
#pragma unroll
                        for (int r = 0; r < 4; ++r) {
                            const int rw = rl + r;
                            const int ch = (nt * 4 + (mh >> 2)) ^ rw;
                            stg[rw * 320 + ch * 4 + (mh & 3)] = accA[nt][r] + bi;
                        }
                    }
#pragma unroll
                    for (int nt = 0; nt < 4; ++nt) {
#pragma unroll
                        for (int r = 0; r < 4; ++r) {
                            const int rw = rl + r;
#pragma unroll
                            for (int k = 0; k < 3; ++k) {
                                const int f = 128 + 3 * (nt * 16 + mh) + k;
                                const int ch = (f >> 2) ^ rw;
                                stg[rw * 320 + ch * 4 + (f & 3)] = accV[k][nt][r];
                            }
                        }
                    }
                }
                asm volatile("s_waitcnt lgkmcnt(0)" ::: "memory");
                __builtin_amdgcn_sched_barrier(0);
                // --- drain: all 64 lanes; each store instr = 1KB contiguous ---
                float* gbase = out + (strip_row0 + p * 8) * 320;
#pragma unroll
                for (int i = 0; i < 10; ++i) {
                    const int v  = i * 64 + lane;     // f32x4 index in pass
                    const int rw = v / 80;
                    const int ch = (v % 80) ^ rw;
                    f32x4 d = *(const f32x4*)(stg + rw * 320 + ch * 4);
                    __builtin_nontemporal_store(d, (f32x4*)(gbase + v * 4));
                }
            }
        } else {
            // partial tail strip: old scalar guarded path
            const int rowg0 = strip_row0 + 4 * kq;
#pragma unroll
            for (int nt = 0; nt < 8; ++nt) {
                const float bi = bias[nt * 16 + mh];
#pragma unroll
                for (int r = 0; r < 4; ++r) {
                    const int rowg = rowg0 + r;
                    if (rowg < N)
                        __builtin_nontemporal_store(accA[nt][r] + bi,
                                                    out + rowg * 320 + nt * 16 + mh);
                }
            }
#pragma unroll
            for (int r = 0; r < 4; ++r) {
                const int rowg = rowg0 + r;
                if (rowg < N) {
#pragma unroll
                    for (int nt = 0; nt < 4; ++nt) {
                        const int w = nt * 16 + mh;
                        f32x3 o;
                        o.x = accV[0][nt][r];
                        o.y = accV[1][nt][r];
                        o.z = accV[2][nt][r];
                        __builtin_nontemporal_store(o,
                            (f32x3*)(out + rowg * 320 + 128 + 3 * w));
                    }
                }
            }
        }
    }
}

extern "C" void kernel_launch(void* const* d_in, const int* in_sizes, int n_in,
                              void* d_out, int out_size, void* d_ws, size_t ws_size,
                              hipStream_t stream)
{
    const float* din1 = (const float*)d_in[0];
    const float* din2 = (const float*)d_in[1];
    const float* W00  = (const float*)d_in[2];
    const float* W01  = (const float*)d_in[3];
    const float* W10  = (const float*)d_in[4];
    const float* W11  = (const float*)d_in[5];
    const float* bias = (const float*)d_in[6];
    float* outp = (float*)d_out;
    __bf16* ws = (__bf16*)d_ws;

    const int N = in_sizes[0] / 320;
    const int nstrips = (N + 15) / 16;          // 16 rows per wave
    const int nblocks = (nstrips + 3) / 4;      // 4 waves per 256-thread block

    // 4608 weight chunks, one bf16_8 per thread
    hipLaunchKernelGGL(tp_convert_weights, dim3(18), dim3(256), 0, stream,
                       W00, W01, W10, W11, ws);
    hipLaunchKernelGGL(tp_main_kernel, dim3(nblocks), dim3(256), 0, stream,
                       din1, din2, ws, bias, outp, N, nstrips);
}